// Round 1
// baseline (781.705 us; speedup 1.0000x reference)
//
#include <hip/hip_runtime.h>

#define RES 512
#define NPIX (RES * RES)   // 262144 texels per plane
#define CH 32

typedef float f32x4 __attribute__((ext_vector_type(4)));

// ---------------------------------------------------------------------------
// Kernel 1: transpose each plane (C,H,W) -> (H,W,C) so one texel's 32
// channels are contiguous (128 B). LDS 32x64 tile; nontemporal loads (source
// is dead after this), cached stores (gather kernel wants these in L2/L3).
// ---------------------------------------------------------------------------
__global__ __launch_bounds__(256) void transpose_chw_hwc(
    const float* __restrict__ p0, const float* __restrict__ p1,
    const float* __restrict__ p2, float* __restrict__ out)
{
    __shared__ float tile[CH][65];   // +1 pad breaks power-of-2 bank strides
    const int plane = blockIdx.y;
    const float* __restrict__ in = (plane == 0) ? p0 : ((plane == 1) ? p1 : p2);
    float* __restrict__ o = out + (size_t)plane * NPIX * CH;
    const int pix0 = blockIdx.x * 64;
    const int t = (int)threadIdx.x;

    // Load 32 channels x 64 pixels = 512 float4; 2 per thread, coalesced rows.
    #pragma unroll
    for (int i = 0; i < 2; ++i) {
        int idx = t + i * 256;       // 0..511
        int c   = idx >> 4;          // 0..31
        int p4  = idx & 15;          // 0..15 (float4 index within 64 pixels)
        f32x4 v = __builtin_nontemporal_load(
            (const f32x4*)(in + (size_t)c * NPIX + pix0 + p4 * 4));
        tile[c][p4 * 4 + 0] = v.x;
        tile[c][p4 * 4 + 1] = v.y;
        tile[c][p4 * 4 + 2] = v.z;
        tile[c][p4 * 4 + 3] = v.w;
    }
    __syncthreads();

    // Store: consecutive threads write consecutive channel-float4s ->
    // 64 pixels x 128 B fully contiguous per tile.
    #pragma unroll
    for (int i = 0; i < 2; ++i) {
        int idx = t + i * 256;       // 0..511
        int p   = idx >> 3;          // 0..63
        int c4  = idx & 7;           // 0..7
        f32x4 v;
        v.x = tile[c4 * 4 + 0][p];
        v.y = tile[c4 * 4 + 1][p];
        v.z = tile[c4 * 4 + 2][p];
        v.w = tile[c4 * 4 + 3][p];
        *(f32x4*)(o + (size_t)(pix0 + p) * CH + c4 * 4) = v;
    }
}

// ---------------------------------------------------------------------------
// Kernel 2: per point, bilinear-sample 3 transposed planes and sum.
// 8 lanes per point, one float4 (4 channels) per lane: every corner load is
// a coalesced, fully-used 128 B transaction per point-group. Nontemporal
// output stores keep the planes resident in L3.
// ---------------------------------------------------------------------------
__global__ __launch_bounds__(256) void triplane_gather(
    const float* __restrict__ xyz, const float* __restrict__ tp,
    float* __restrict__ out, int npts)
{
    int gid = blockIdx.x * 256 + (int)threadIdx.x;
    int n  = gid >> 3;
    int c4 = gid & 7;
    if (n >= npts) return;

    float cx = xyz[n * 3 + 0];
    float cy = xyz[n * 3 + 1];
    float cz = xyz[n * 3 + 2];

    // plane 0 (T_xy): W<-x, H<-y ; plane 1 (T_yz): W<-y, H<-z ; plane 2 (T_zx): W<-z, H<-x
    float wcoord[3] = {cx, cy, cz};
    float hcoord[3] = {cy, cz, cx};

    f32x4 acc = {0.0f, 0.0f, 0.0f, 0.0f};

    #pragma unroll
    for (int pl = 0; pl < 3; ++pl) {
        const float* __restrict__ tpp = tp + (size_t)pl * NPIX * CH;
        // align_corners=False mapping: ((c+1)*RES - 1) * 0.5
        float fx = (wcoord[pl] + 1.0f) * (0.5f * RES) - 0.5f;
        float fy = (hcoord[pl] + 1.0f) * (0.5f * RES) - 0.5f;
        float x0 = floorf(fx), y0 = floorf(fy);
        float wx1 = fx - x0, wy1 = fy - y0;
        float wx0 = 1.0f - wx1, wy0 = 1.0f - wy1;
        int ix0 = (int)x0, iy0 = (int)y0;
        int ix1 = ix0 + 1, iy1 = iy0 + 1;
        // zero-padding: validity is separable across axes
        if (ix0 < 0 || ix0 >= RES) wx0 = 0.0f;
        if (ix1 < 0 || ix1 >= RES) wx1 = 0.0f;
        if (iy0 < 0 || iy0 >= RES) wy0 = 0.0f;
        if (iy1 < 0 || iy1 >= RES) wy1 = 0.0f;
        int jx0 = min(max(ix0, 0), RES - 1);
        int jx1 = min(max(ix1, 0), RES - 1);
        int jy0 = min(max(iy0, 0), RES - 1);
        int jy1 = min(max(iy1, 0), RES - 1);

        const f32x4* r0 = (const f32x4*)(tpp + (size_t)(jy0 * RES) * CH) + c4;
        const f32x4* r1 = (const f32x4*)(tpp + (size_t)(jy1 * RES) * CH) + c4;
        f32x4 v00 = r0[(size_t)jx0 * (CH / 4)];
        f32x4 v01 = r0[(size_t)jx1 * (CH / 4)];
        f32x4 v10 = r1[(size_t)jx0 * (CH / 4)];
        f32x4 v11 = r1[(size_t)jx1 * (CH / 4)];

        acc += (wy0 * wx0) * v00 + (wy0 * wx1) * v01 +
               (wy1 * wx0) * v10 + (wy1 * wx1) * v11;
    }

    __builtin_nontemporal_store(acc, (f32x4*)(out + (size_t)n * CH + c4 * 4));
}

// ---------------------------------------------------------------------------
// Fallback (only if d_ws can't hold the 96 MB transposed planes):
// direct gather from (C,H,W) layout, 1 lane per (point, channel).
// ---------------------------------------------------------------------------
__global__ __launch_bounds__(256) void triplane_direct(
    const float* __restrict__ xyz,
    const float* __restrict__ p0, const float* __restrict__ p1,
    const float* __restrict__ p2, float* __restrict__ out, int npts)
{
    long long gid = (long long)blockIdx.x * 256 + threadIdx.x;
    int n = (int)(gid >> 5);
    int c = (int)(gid & 31);
    if (n >= npts) return;

    float cx = xyz[n * 3 + 0];
    float cy = xyz[n * 3 + 1];
    float cz = xyz[n * 3 + 2];
    const float* planes[3] = {p0, p1, p2};
    float wcoord[3] = {cx, cy, cz};
    float hcoord[3] = {cy, cz, cx};

    float acc = 0.0f;
    #pragma unroll
    for (int pl = 0; pl < 3; ++pl) {
        float fx = (wcoord[pl] + 1.0f) * (0.5f * RES) - 0.5f;
        float fy = (hcoord[pl] + 1.0f) * (0.5f * RES) - 0.5f;
        float x0 = floorf(fx), y0 = floorf(fy);
        float wx1 = fx - x0, wy1 = fy - y0;
        float wx0 = 1.0f - wx1, wy0 = 1.0f - wy1;
        int ix0 = (int)x0, iy0 = (int)y0;
        int ix1 = ix0 + 1, iy1 = iy0 + 1;
        if (ix0 < 0 || ix0 >= RES) wx0 = 0.0f;
        if (ix1 < 0 || ix1 >= RES) wx1 = 0.0f;
        if (iy0 < 0 || iy0 >= RES) wy0 = 0.0f;
        if (iy1 < 0 || iy1 >= RES) wy1 = 0.0f;
        int jx0 = min(max(ix0, 0), RES - 1);
        int jx1 = min(max(ix1, 0), RES - 1);
        int jy0 = min(max(iy0, 0), RES - 1);
        int jy1 = min(max(iy1, 0), RES - 1);

        const float* pc = planes[pl] + (size_t)c * NPIX;
        float v00 = pc[jy0 * RES + jx0];
        float v01 = pc[jy0 * RES + jx1];
        float v10 = pc[jy1 * RES + jx0];
        float v11 = pc[jy1 * RES + jx1];
        acc += (wy0 * wx0) * v00 + (wy0 * wx1) * v01 +
               (wy1 * wx0) * v10 + (wy1 * wx1) * v11;
    }
    out[(size_t)n * CH + c] = acc;
}

extern "C" void kernel_launch(void* const* d_in, const int* in_sizes, int n_in,
                              void* d_out, int out_size, void* d_ws, size_t ws_size,
                              hipStream_t stream) {
    const float* xyz = (const float*)d_in[0];
    const float* Txy = (const float*)d_in[1];
    const float* Tyz = (const float*)d_in[2];
    const float* Tzx = (const float*)d_in[3];
    float* out = (float*)d_out;
    const int npts = in_sizes[0] / 3;

    const size_t need = (size_t)3 * NPIX * CH * sizeof(float);  // 96 MB
    if (ws_size >= need) {
        float* tp = (float*)d_ws;
        dim3 tgrid(NPIX / 64, 3);   // 4096 tiles x 3 planes
        transpose_chw_hwc<<<tgrid, 256, 0, stream>>>(Txy, Tyz, Tzx, tp);
        long long total = (long long)npts * 8;   // 8 lanes per point
        triplane_gather<<<(int)((total + 255) / 256), 256, 0, stream>>>(
            xyz, tp, out, npts);
    } else {
        long long total = (long long)npts * 32;  // 1 lane per (point, channel)
        triplane_direct<<<(int)((total + 255) / 256), 256, 0, stream>>>(
            xyz, Txy, Tyz, Tzx, out, npts);
    }
}

// Round 2
// 668.199 us; speedup vs baseline: 1.1699x; 1.1699x over previous
//
#include <hip/hip_runtime.h>

#define RES 512
#define NPIX (RES * RES)   // 262144 texels per plane
#define CH 32

typedef float f32x4 __attribute__((ext_vector_type(4)));
typedef float f32x8 __attribute__((ext_vector_type(8)));
typedef _Float16 f16x8 __attribute__((ext_vector_type(8)));

// ---------------------------------------------------------------------------
// Kernel 1: transpose + downconvert each plane (C,H,W) fp32 -> (H,W,C) fp16.
// Tile = 32 channels x 256 pixels. Each wave reads one full channel row
// (1 KB contiguous) per pass -> perfectly coalesced. Stores are fully
// contiguous 16 KB/block of fp16. Plain cached loads (the nontemporal loads
// in round 1 ran at 0.65 TB/s).
// ---------------------------------------------------------------------------
__global__ __launch_bounds__(256) void transpose_chw_hwc_f16(
    const float* __restrict__ p0, const float* __restrict__ p1,
    const float* __restrict__ p2, _Float16* __restrict__ out)
{
    __shared__ float tile[CH][257];   // +1 pad; 32.9 KB
    const int plane = blockIdx.y;
    const float* __restrict__ in = (plane == 0) ? p0 : ((plane == 1) ? p1 : p2);
    _Float16* __restrict__ o = out + (size_t)plane * NPIX * CH;
    const int pix0 = blockIdx.x * 256;
    const int t = (int)threadIdx.x;

    // Load 32 ch x 256 px; 8 passes x 256 threads x float4.
    // Per pass each wave covers one channel row: 64 x 16 B = 1 KB contiguous.
    #pragma unroll
    for (int i = 0; i < 8; ++i) {
        int idx = t + i * 256;       // 0..2047
        int c   = idx >> 6;          // 0..31
        int p4  = idx & 63;          // float4 index within 256 pixels
        f32x4 v = *(const f32x4*)(in + (size_t)c * NPIX + pix0 + p4 * 4);
        tile[c][p4 * 4 + 0] = v.x;
        tile[c][p4 * 4 + 1] = v.y;
        tile[c][p4 * 4 + 2] = v.z;
        tile[c][p4 * 4 + 3] = v.w;
    }
    __syncthreads();

    // Store 256 px x 32 ch fp16 = 16 KB contiguous; 4 passes x 16 B/thread.
    #pragma unroll
    for (int i = 0; i < 4; ++i) {
        int idx = t + i * 256;       // 0..1023
        int p   = idx >> 2;          // 0..255
        int c8  = idx & 3;           // which group of 8 channels
        f16x8 h;
        #pragma unroll
        for (int k = 0; k < 8; ++k)
            h[k] = (_Float16)tile[c8 * 8 + k][p];
        *((f16x8*)(o + (size_t)(pix0 + p) * CH) + c8) = h;
    }
}

// ---------------------------------------------------------------------------
// Kernel 2: bilinear gather from fp16 (H,W,C) planes. 4 lanes per point,
// one f16x8 (8 channels, 16 B) per lane -> every corner is a coalesced
// 64 B/point segment. fp32 accumulate; nontemporal 32 B output stores keep
// the 48 MB of planes resident in cache instead of the 256 MB out stream.
// ---------------------------------------------------------------------------
__global__ __launch_bounds__(256) void triplane_gather_f16(
    const float* __restrict__ xyz, const _Float16* __restrict__ tp,
    float* __restrict__ out, int npts)
{
    int gid = blockIdx.x * 256 + (int)threadIdx.x;
    int n  = gid >> 2;
    int c8 = gid & 3;
    if (n >= npts) return;

    float cx = xyz[n * 3 + 0];
    float cy = xyz[n * 3 + 1];
    float cz = xyz[n * 3 + 2];

    // plane 0 (T_xy): W<-x H<-y ; plane 1 (T_yz): W<-y H<-z ; plane 2 (T_zx): W<-z H<-x
    float wcoord[3] = {cx, cy, cz};
    float hcoord[3] = {cy, cz, cx};

    f32x8 acc = {0.f, 0.f, 0.f, 0.f, 0.f, 0.f, 0.f, 0.f};

    #pragma unroll
    for (int pl = 0; pl < 3; ++pl) {
        const _Float16* __restrict__ tpp = tp + (size_t)pl * NPIX * CH;
        float fx = (wcoord[pl] + 1.0f) * (0.5f * RES) - 0.5f;
        float fy = (hcoord[pl] + 1.0f) * (0.5f * RES) - 0.5f;
        float x0 = floorf(fx), y0 = floorf(fy);
        float wx1 = fx - x0, wy1 = fy - y0;
        float wx0 = 1.0f - wx1, wy0 = 1.0f - wy1;
        int ix0 = (int)x0, iy0 = (int)y0;
        int ix1 = ix0 + 1, iy1 = iy0 + 1;
        // zero-padding: validity is separable per axis
        if (ix0 < 0 || ix0 >= RES) wx0 = 0.0f;
        if (ix1 < 0 || ix1 >= RES) wx1 = 0.0f;
        if (iy0 < 0 || iy0 >= RES) wy0 = 0.0f;
        if (iy1 < 0 || iy1 >= RES) wy1 = 0.0f;
        int jx0 = min(max(ix0, 0), RES - 1);
        int jx1 = min(max(ix1, 0), RES - 1);
        int jy0 = min(max(iy0, 0), RES - 1);
        int jy1 = min(max(iy1, 0), RES - 1);

        const f16x8* r0 = (const f16x8*)(tpp + (size_t)(jy0 * RES) * CH) + c8;
        const f16x8* r1 = (const f16x8*)(tpp + (size_t)(jy1 * RES) * CH) + c8;
        f16x8 v00 = r0[jx0 * (CH / 8)];
        f16x8 v01 = r0[jx1 * (CH / 8)];
        f16x8 v10 = r1[jx0 * (CH / 8)];
        f16x8 v11 = r1[jx1 * (CH / 8)];

        acc += (wy0 * wx0) * __builtin_convertvector(v00, f32x8)
             + (wy0 * wx1) * __builtin_convertvector(v01, f32x8)
             + (wy1 * wx0) * __builtin_convertvector(v10, f32x8)
             + (wy1 * wx1) * __builtin_convertvector(v11, f32x8);
    }

    float* op = out + (size_t)n * CH + c8 * 8;
    f32x4 lo = {acc.s0, acc.s1, acc.s2, acc.s3};
    f32x4 hi = {acc.s4, acc.s5, acc.s6, acc.s7};
    __builtin_nontemporal_store(lo, (f32x4*)op);
    __builtin_nontemporal_store(hi, (f32x4*)(op + 4));
}

// ---------------------------------------------------------------------------
// Fallback (d_ws too small for 48 MB of fp16 planes): direct gather from
// (C,H,W) fp32 layout, 1 lane per (point, channel).
// ---------------------------------------------------------------------------
__global__ __launch_bounds__(256) void triplane_direct(
    const float* __restrict__ xyz,
    const float* __restrict__ p0, const float* __restrict__ p1,
    const float* __restrict__ p2, float* __restrict__ out, int npts)
{
    long long gid = (long long)blockIdx.x * 256 + threadIdx.x;
    int n = (int)(gid >> 5);
    int c = (int)(gid & 31);
    if (n >= npts) return;

    float cx = xyz[n * 3 + 0];
    float cy = xyz[n * 3 + 1];
    float cz = xyz[n * 3 + 2];
    const float* planes[3] = {p0, p1, p2};
    float wcoord[3] = {cx, cy, cz};
    float hcoord[3] = {cy, cz, cx};

    float acc = 0.0f;
    #pragma unroll
    for (int pl = 0; pl < 3; ++pl) {
        float fx = (wcoord[pl] + 1.0f) * (0.5f * RES) - 0.5f;
        float fy = (hcoord[pl] + 1.0f) * (0.5f * RES) - 0.5f;
        float x0 = floorf(fx), y0 = floorf(fy);
        float wx1 = fx - x0, wy1 = fy - y0;
        float wx0 = 1.0f - wx1, wy0 = 1.0f - wy1;
        int ix0 = (int)x0, iy0 = (int)y0;
        int ix1 = ix0 + 1, iy1 = iy0 + 1;
        if (ix0 < 0 || ix0 >= RES) wx0 = 0.0f;
        if (ix1 < 0 || ix1 >= RES) wx1 = 0.0f;
        if (iy0 < 0 || iy0 >= RES) wy0 = 0.0f;
        if (iy1 < 0 || iy1 >= RES) wy1 = 0.0f;
        int jx0 = min(max(ix0, 0), RES - 1);
        int jx1 = min(max(ix1, 0), RES - 1);
        int jy0 = min(max(iy0, 0), RES - 1);
        int jy1 = min(max(iy1, 0), RES - 1);

        const float* pc = planes[pl] + (size_t)c * NPIX;
        float v00 = pc[jy0 * RES + jx0];
        float v01 = pc[jy0 * RES + jx1];
        float v10 = pc[jy1 * RES + jx0];
        float v11 = pc[jy1 * RES + jx1];
        acc += (wy0 * wx0) * v00 + (wy0 * wx1) * v01 +
               (wy1 * wx0) * v10 + (wy1 * wx1) * v11;
    }
    out[(size_t)n * CH + c] = acc;
}

extern "C" void kernel_launch(void* const* d_in, const int* in_sizes, int n_in,
                              void* d_out, int out_size, void* d_ws, size_t ws_size,
                              hipStream_t stream) {
    const float* xyz = (const float*)d_in[0];
    const float* Txy = (const float*)d_in[1];
    const float* Tyz = (const float*)d_in[2];
    const float* Tzx = (const float*)d_in[3];
    float* out = (float*)d_out;
    const int npts = in_sizes[0] / 3;

    const size_t need = (size_t)3 * NPIX * CH * sizeof(_Float16);  // 48 MB
    if (ws_size >= need) {
        _Float16* tp = (_Float16*)d_ws;
        dim3 tgrid(NPIX / 256, 3);   // 1024 tiles x 3 planes
        transpose_chw_hwc_f16<<<tgrid, 256, 0, stream>>>(Txy, Tyz, Tzx, tp);
        long long total = (long long)npts * 4;   // 4 lanes per point
        triplane_gather_f16<<<(int)((total + 255) / 256), 256, 0, stream>>>(
            xyz, tp, out, npts);
    } else {
        long long total = (long long)npts * 32;  // 1 lane per (point, channel)
        triplane_direct<<<(int)((total + 255) / 256), 256, 0, stream>>>(
            xyz, Txy, Tyz, Tzx, out, npts);
    }
}